// Round 1
// baseline (543.501 us; speedup 1.0000x reference)
//
#include <hip/hip_runtime.h>
#include <math.h>

// Problem shape (fixed by reference setup_inputs)
#define B_DIM 64
#define CIN   512
#define COUT  512
#define A_DIM 32
#define HW    3136      // 56*56
#define HW4   784       // HW/4 float4s per row (784 = 3*256 + 16)
#define BN_EPS 1e-5f

// ---------------------------------------------------------------------------
// Kernel 1: global average pool. One block per (b, c) row of 3136 floats.
// Fully coalesced float4 loads; wave shuffle reduce; LDS combine.
// HBM-bound: reads 411 MB total.
// ---------------------------------------------------------------------------
__global__ __launch_bounds__(256) void pool_kernel(const float* __restrict__ x,
                                                   float* __restrict__ pooled) {
    const int row = blockIdx.x;                    // b*CIN + c
    const float4* xr = (const float4*)(x + (size_t)row * HW);
    const int t = threadIdx.x;

    float4 v0 = xr[t];
    float4 v1 = xr[t + 256];
    float4 v2 = xr[t + 512];
    float s = (v0.x + v0.y) + (v0.z + v0.w)
            + (v1.x + v1.y) + (v1.z + v1.w)
            + (v2.x + v2.y) + (v2.z + v2.w);
    if (t < 16) {
        float4 v3 = xr[t + 768];
        s += (v3.x + v3.y) + (v3.z + v3.w);
    }

    // wave64 butterfly reduce
    #pragma unroll
    for (int off = 32; off > 0; off >>= 1)
        s += __shfl_down(s, off, 64);

    __shared__ float wsum[4];
    if ((t & 63) == 0) wsum[t >> 6] = s;
    __syncthreads();
    if (t == 0) {
        float tot = (wsum[0] + wsum[1]) + (wsum[2] + wsum[3]);
        pooled[row] = tot * (1.0f / (float)HW);
    }
}

// ---------------------------------------------------------------------------
// Kernel 2: the whole attention head for one batch element per block.
//   h = BN(ReLU-after)(pooled @ fc_w^T)          [A=32]
//   ch_att = sigmoid(h @ channel_fc_w^T + b)     [512]
//   f_att  = sigmoid(h @ filter_fc_w^T + b)      [512]
// Tiny: 64 blocks, all weights L2-resident (64 KB each).
// ---------------------------------------------------------------------------
__global__ __launch_bounds__(256) void att_kernel(
    const float* __restrict__ pooled,
    const float* __restrict__ fc_w,        // [A, CIN]
    const float* __restrict__ bn_gamma,
    const float* __restrict__ bn_beta,
    const float* __restrict__ bn_mean,
    const float* __restrict__ bn_var,
    const float* __restrict__ ch_w,        // [CIN, A]
    const float* __restrict__ ch_b,        // [CIN]
    const float* __restrict__ f_w,         // [COUT, A]
    const float* __restrict__ f_b,         // [COUT]
    float* __restrict__ out)               // [B*CIN] ch_att ++ [B*COUT] f_att
{
    const int b = blockIdx.x;
    const int t = threadIdx.x;

    __shared__ float p[CIN];
    __shared__ float part[A_DIM][8];
    __shared__ float h[A_DIM];

    p[t]       = pooled[b * CIN + t];
    p[t + 256] = pooled[b * CIN + t + 256];
    __syncthreads();

    // h[a] partials: 8 threads per a, stride-8 over c (conflict-free LDS:
    // 8 distinct addresses -> 8 distinct banks, 8-lane same-address broadcast)
    const int a = t >> 3;
    const int j = t & 7;
    {
        const float* wrow = fc_w + a * CIN;
        float s = 0.f;
        #pragma unroll
        for (int k = 0; k < 64; ++k) {
            const int c = j + (k << 3);
            s += p[c] * wrow[c];
        }
        part[a][j] = s;
    }
    __syncthreads();

    if (t < A_DIM) {
        float tot = 0.f;
        #pragma unroll
        for (int jj = 0; jj < 8; ++jj) tot += part[t][jj];
        const float inv = 1.0f / sqrtf(bn_var[t] + BN_EPS);
        float hv = (tot - bn_mean[t]) * (bn_gamma[t] * inv) + bn_beta[t];
        h[t] = hv > 0.f ? hv : 0.f;
    }
    __syncthreads();

    // Each thread produces 2 channel-att and 2 filter-att outputs.
    #pragma unroll
    for (int rep = 0; rep < 2; ++rep) {
        const int c = t + rep * 256;
        float sc = ch_b[c];
        float sf = f_b[c];
        const float* cw = ch_w + c * A_DIM;
        const float* fw = f_w + c * A_DIM;
        #pragma unroll
        for (int a2 = 0; a2 < A_DIM; ++a2) {
            const float hv = h[a2];          // broadcast read, free
            sc += hv * cw[a2];
            sf += hv * fw[a2];
        }
        out[b * CIN + c]                 = 1.0f / (1.0f + expf(-sc));
        out[B_DIM * CIN + b * COUT + c]  = 1.0f / (1.0f + expf(-sf));
    }
}

extern "C" void kernel_launch(void* const* d_in, const int* in_sizes, int n_in,
                              void* d_out, int out_size, void* d_ws, size_t ws_size,
                              hipStream_t stream) {
    const float* x        = (const float*)d_in[0];
    const float* fc_w     = (const float*)d_in[1];
    const float* bn_gamma = (const float*)d_in[2];
    const float* bn_beta  = (const float*)d_in[3];
    const float* bn_mean  = (const float*)d_in[4];
    const float* bn_var   = (const float*)d_in[5];
    const float* ch_w     = (const float*)d_in[6];
    const float* ch_b     = (const float*)d_in[7];
    const float* f_w      = (const float*)d_in[8];
    const float* f_b      = (const float*)d_in[9];
    float* out = (float*)d_out;

    float* pooled = (float*)d_ws;   // B_DIM*CIN floats = 128 KB

    pool_kernel<<<B_DIM * CIN, 256, 0, stream>>>(x, pooled);
    att_kernel<<<B_DIM, 256, 0, stream>>>(pooled, fc_w, bn_gamma, bn_beta,
                                          bn_mean, bn_var, ch_w, ch_b,
                                          f_w, f_b, out);
}

// Round 2
// 514.172 us; speedup vs baseline: 1.0570x; 1.0570x over previous
//
#include <hip/hip_runtime.h>
#include <math.h>

// Problem shape (fixed by reference setup_inputs)
#define B_DIM 64
#define CIN   512
#define COUT  512
#define A_DIM 32
#define HW    3136      // 56*56
#define BN_EPS 1e-5f

typedef float f4 __attribute__((ext_vector_type(4)));

// ---------------------------------------------------------------------------
// Kernel 1: global average pool. ONE WAVE per (b, c) row of 3136 floats
// (784 float4 = 12 full wave-passes + 16-lane tail). No LDS, no barrier —
// pure shuffle reduce. Nontemporal loads: x is 411 MB read-once streaming.
// HBM floor: 411 MB / 6.5 TB/s ~= 63 us.
// ---------------------------------------------------------------------------
__global__ __launch_bounds__(256) void pool_kernel(const float* __restrict__ x,
                                                   float* __restrict__ pooled) {
    const int row  = (blockIdx.x << 2) | (threadIdx.x >> 6);   // global wave id
    const int lane = threadIdx.x & 63;
    const f4* xr = (const f4*)(x + (size_t)row * HW);

    f4 acc = {0.f, 0.f, 0.f, 0.f};
    #pragma unroll
    for (int k = 0; k < 12; ++k) {
        f4 v = __builtin_nontemporal_load(xr + lane + (k << 6));
        acc += v;
    }
    if (lane < 16) {
        f4 v = __builtin_nontemporal_load(xr + 768 + lane);
        acc += v;
    }
    float s = (acc.x + acc.y) + (acc.z + acc.w);

    // wave64 reduce
    #pragma unroll
    for (int off = 32; off > 0; off >>= 1)
        s += __shfl_down(s, off, 64);

    if (lane == 0)
        pooled[row] = s * (1.0f / (float)HW);
}

// ---------------------------------------------------------------------------
// Kernel 2: the whole attention head for one batch element per block.
//   h = ReLU(BN(pooled @ fc_w^T))                [A=32]
//   ch_att = sigmoid(h @ channel_fc_w^T + b)     [512]
//   f_att  = sigmoid(h @ filter_fc_w^T + b)      [512]
// Tiny: 64 blocks; weights (3 x 64 KB) are L2-resident.
// ---------------------------------------------------------------------------
__global__ __launch_bounds__(256) void att_kernel(
    const float* __restrict__ pooled,
    const float* __restrict__ fc_w,        // [A, CIN]
    const float* __restrict__ bn_gamma,
    const float* __restrict__ bn_beta,
    const float* __restrict__ bn_mean,
    const float* __restrict__ bn_var,
    const float* __restrict__ ch_w,        // [CIN, A]
    const float* __restrict__ ch_b,        // [CIN]
    const float* __restrict__ f_w,         // [COUT, A]
    const float* __restrict__ f_b,         // [COUT]
    float* __restrict__ out)               // [B*CIN] ch_att ++ [B*COUT] f_att
{
    const int b = blockIdx.x;
    const int t = threadIdx.x;

    __shared__ float p[CIN];
    __shared__ float part[A_DIM][8];
    __shared__ float h[A_DIM];

    p[t]       = pooled[b * CIN + t];
    p[t + 256] = pooled[b * CIN + t + 256];
    __syncthreads();

    // h[a] partials: 8 threads per a, stride-8 over c (8 distinct banks,
    // same-address broadcast within each bank group -> conflict-free)
    const int a = t >> 3;
    const int j = t & 7;
    {
        const float* wrow = fc_w + a * CIN;
        float s = 0.f;
        #pragma unroll
        for (int k = 0; k < 64; ++k) {
            const int c = j + (k << 3);
            s += p[c] * wrow[c];
        }
        part[a][j] = s;
    }
    __syncthreads();

    if (t < A_DIM) {
        float tot = 0.f;
        #pragma unroll
        for (int jj = 0; jj < 8; ++jj) tot += part[t][jj];
        const float inv = 1.0f / sqrtf(bn_var[t] + BN_EPS);
        float hv = (tot - bn_mean[t]) * (bn_gamma[t] * inv) + bn_beta[t];
        h[t] = hv > 0.f ? hv : 0.f;
    }
    __syncthreads();

    // Each thread produces 2 channel-att and 2 filter-att outputs.
    #pragma unroll
    for (int rep = 0; rep < 2; ++rep) {
        const int c = t + rep * 256;
        float sc = ch_b[c];
        float sf = f_b[c];
        const float* cw = ch_w + c * A_DIM;
        const float* fw = f_w + c * A_DIM;
        #pragma unroll
        for (int a2 = 0; a2 < A_DIM; ++a2) {
            const float hv = h[a2];          // LDS broadcast read, free
            sc += hv * cw[a2];
            sf += hv * fw[a2];
        }
        out[b * CIN + c]                 = 1.0f / (1.0f + expf(-sc));
        out[B_DIM * CIN + b * COUT + c]  = 1.0f / (1.0f + expf(-sf));
    }
}

extern "C" void kernel_launch(void* const* d_in, const int* in_sizes, int n_in,
                              void* d_out, int out_size, void* d_ws, size_t ws_size,
                              hipStream_t stream) {
    const float* x        = (const float*)d_in[0];
    const float* fc_w     = (const float*)d_in[1];
    const float* bn_gamma = (const float*)d_in[2];
    const float* bn_beta  = (const float*)d_in[3];
    const float* bn_mean  = (const float*)d_in[4];
    const float* bn_var   = (const float*)d_in[5];
    const float* ch_w     = (const float*)d_in[6];
    const float* ch_b     = (const float*)d_in[7];
    const float* f_w      = (const float*)d_in[8];
    const float* f_b      = (const float*)d_in[9];
    float* out = (float*)d_out;

    float* pooled = (float*)d_ws;   // B_DIM*CIN floats = 128 KB

    // wave-per-row: B*CIN rows, 4 rows per 256-thread block
    pool_kernel<<<(B_DIM * CIN) / 4, 256, 0, stream>>>(x, pooled);
    att_kernel<<<B_DIM, 256, 0, stream>>>(pooled, fc_w, bn_gamma, bn_beta,
                                          bn_mean, bn_var, ch_w, ch_b,
                                          f_w, f_b, out);
}